// Round 1
// baseline (553.961 us; speedup 1.0000x reference)
//
#include <hip/hip_runtime.h>
#include <hip/hip_bf16.h>
#include <math.h>

#define N_TOKENS 16384
#define D_MODEL  4096
#define N_EXP    64

// ---------------------------------------------------------------------------
// Kernel T: transpose gate_w [64][4096] -> wt [4096][64]
// so that for a fixed d, all 64 expert weights are contiguous (scalar-load
// friendly: the GEMM kernel indexes them wave-uniformly).
// ---------------------------------------------------------------------------
__global__ void router_transpose(const float* __restrict__ w,
                                 float* __restrict__ wt) {
    int idx = blockIdx.x * 256 + threadIdx.x;   // 0 .. 64*4096-1
    int e = idx >> 12;        // / 4096
    int d = idx & 4095;       // % 4096
    wt[d * N_EXP + e] = w[idx];
}

// ---------------------------------------------------------------------------
// Kernel A: partial GEMM. Thread-per-token, 64 fp32 accumulators.
// grid = (64 token-chunks, n_slices d-slices), block = 256.
// w index is wave-uniform -> compiler emits scalar loads, FMAs use SGPR src.
// ---------------------------------------------------------------------------
__global__ void __launch_bounds__(256)
router_gemm(const float* __restrict__ x, const float* __restrict__ wt,
            float* __restrict__ partial, int dlen) {
    int token = blockIdx.x * 256 + threadIdx.x;
    int d0 = blockIdx.y * dlen;

    float acc[N_EXP];
#pragma unroll
    for (int e = 0; e < N_EXP; ++e) acc[e] = 0.f;

    const float4* xv = (const float4*)(x + (size_t)token * D_MODEL + d0);
    const float* wp = wt + (size_t)d0 * N_EXP;
    int iters = dlen >> 2;

    for (int i = 0; i < iters; ++i) {
        float4 xq = xv[i];
        const float* wr = wp + (size_t)i * (4 * N_EXP);
#pragma unroll
        for (int e = 0; e < N_EXP; ++e) {
            float a = acc[e];
            a = fmaf(xq.x, wr[e],             a);
            a = fmaf(xq.y, wr[N_EXP + e],     a);
            a = fmaf(xq.z, wr[2 * N_EXP + e], a);
            a = fmaf(xq.w, wr[3 * N_EXP + e], a);
            acc[e] = a;
        }
    }

    float4* po = (float4*)(partial + (size_t)blockIdx.y * N_TOKENS * N_EXP
                                   + (size_t)token * N_EXP);
#pragma unroll
    for (int e = 0; e < 16; ++e)
        po[e] = make_float4(acc[4*e], acc[4*e+1], acc[4*e+2], acc[4*e+3]);
}

// ---------------------------------------------------------------------------
// Kernel B: reduce slices -> logits, softmax, top-2, outputs, p_i/f_i sums.
// One wave per token (lane = expert). grid = 512, block = 256 (4 waves).
// Each block handles 32 tokens (8 iterations x 4 waves).
// ---------------------------------------------------------------------------
__global__ void __launch_bounds__(256)
router_phaseB(const float* __restrict__ partial, int n_slices,
              float* __restrict__ out,
              float* __restrict__ p_sum, float* __restrict__ f_sum) {
    __shared__ float p_acc[4][N_EXP];
    __shared__ float f_acc[4][N_EXP];

    int tid = threadIdx.x;
    int wave = tid >> 6;
    int lane = tid & 63;

    p_acc[wave][lane] = 0.f;
    f_acc[wave][lane] = 0.f;

    for (int it = 0; it < 8; ++it) {
        int token = blockIdx.x * 32 + it * 4 + wave;

        // reduce partial logits across slices (coalesced 256B per wave)
        float logit = 0.f;
        size_t base = (size_t)token * N_EXP + lane;
        for (int s = 0; s < n_slices; ++s)
            logit += partial[(size_t)s * N_TOKENS * N_EXP + base];

        // softmax over 64 lanes
        float m = logit;
#pragma unroll
        for (int off = 1; off < 64; off <<= 1)
            m = fmaxf(m, __shfl_xor(m, off, 64));
        float p = expf(logit - m);
        float denom = p;
#pragma unroll
        for (int off = 1; off < 64; off <<= 1)
            denom += __shfl_xor(denom, off, 64);
        float prob = p / denom;

        p_acc[wave][lane] += prob;

        // top-1 (ties -> lower index, matching jax.lax.top_k)
        float v1 = prob; int i1 = lane;
#pragma unroll
        for (int off = 1; off < 64; off <<= 1) {
            float ov = __shfl_xor(v1, off, 64);
            int   oi = __shfl_xor(i1, off, 64);
            if (ov > v1 || (ov == v1 && oi < i1)) { v1 = ov; i1 = oi; }
        }
        // top-2: exclude i1
        float v2 = (lane == i1) ? -__builtin_inff() : prob;
        int i2 = lane;
#pragma unroll
        for (int off = 1; off < 64; off <<= 1) {
            float ov = __shfl_xor(v2, off, 64);
            int   oi = __shfl_xor(i2, off, 64);
            if (ov > v2 || (ov == v2 && oi < i2)) { v2 = ov; i2 = oi; }
        }

        if (lane == i1) f_acc[wave][lane] += 1.f;

        if (lane == 0) {
            float s12 = v1 + v2;
            ((float2*)out)[token] = make_float2(v1 / s12, v2 / s12);
            ((float2*)(out + 2 * N_TOKENS))[token] =
                make_float2((float)i1, (float)i2);
        }
    }

    __syncthreads();
    if (tid < N_EXP) {
        float ps = p_acc[0][tid] + p_acc[1][tid] + p_acc[2][tid] + p_acc[3][tid];
        float fs = f_acc[0][tid] + f_acc[1][tid] + f_acc[2][tid] + f_acc[3][tid];
        atomicAdd(&p_sum[tid], ps);
        atomicAdd(&f_sum[tid], fs);
    }
}

// ---------------------------------------------------------------------------
// Kernel C: loss = 0.01 * sum_e (f_e/N) * (p_e/N)
// ---------------------------------------------------------------------------
__global__ void router_loss(const float* __restrict__ p_sum,
                            const float* __restrict__ f_sum,
                            float* __restrict__ out) {
    int lane = threadIdx.x;
    float v = f_sum[lane] * p_sum[lane];
#pragma unroll
    for (int off = 1; off < 64; off <<= 1)
        v += __shfl_xor(v, off, 64);
    if (lane == 0)
        out[4 * N_TOKENS] = 0.01f * v / ((float)N_TOKENS * (float)N_TOKENS);
}

// ---------------------------------------------------------------------------
extern "C" void kernel_launch(void* const* d_in, const int* in_sizes, int n_in,
                              void* d_out, int out_size, void* d_ws, size_t ws_size,
                              hipStream_t stream) {
    const float* x = (const float*)d_in[0];
    const float* w = (const float*)d_in[1];
    float* out = (float*)d_out;
    char* ws = (char*)d_ws;

    const size_t WT_BYTES = (size_t)D_MODEL * N_EXP * sizeof(float);   // 1 MiB
    const size_t SUM_BYTES = 2 * N_EXP * sizeof(float);

    // pick the largest d-split whose partial buffer fits in the workspace
    int n_slices = 1;
    for (int c = 8; c >= 1; c >>= 1) {
        size_t need = (size_t)c * N_TOKENS * N_EXP * sizeof(float)
                      + WT_BYTES + SUM_BYTES + 512;
        if (need <= ws_size) { n_slices = c; break; }
    }

    size_t partial_bytes = (size_t)n_slices * N_TOKENS * N_EXP * sizeof(float);
    float* partial = (float*)ws;
    float* wt = (float*)(ws + partial_bytes);
    float* p_sum = (float*)(ws + partial_bytes + WT_BYTES);
    float* f_sum = p_sum + N_EXP;

    hipMemsetAsync(p_sum, 0, SUM_BYTES, stream);

    router_transpose<<<(N_EXP * D_MODEL) / 256, 256, 0, stream>>>(w, wt);

    dim3 gridA(N_TOKENS / 256, n_slices);
    router_gemm<<<gridA, 256, 0, stream>>>(x, wt, partial, D_MODEL / n_slices);

    router_phaseB<<<512, 256, 0, stream>>>(partial, n_slices, out, p_sum, f_sum);

    router_loss<<<1, 64, 0, stream>>>(p_sum, f_sum, out);
}